// Round 3
// baseline (151.208 us; speedup 1.0000x reference)
//
#include <hip/hip_runtime.h>

static constexpr int IH = 480;
static constexpr int IW = 640;
static constexpr int IHW = IH * IW;
static constexpr int NPIX4 = IHW / 4;   // 4 x-pixels per thread; IW % 4 == 0

typedef float f32x4 __attribute__((ext_vector_type(4)));

__global__ __launch_bounds__(256) void prop_kernel(
    const float* __restrict__ depth,
    const float* __restrict__ normal,
    const float* __restrict__ rgb,
    const float* __restrict__ conf,
    const float* __restrict__ Kinv,
    float* __restrict__ out,
    int B)
{
    int tid = blockIdx.x * blockDim.x + threadIdx.x;
    if (tid >= B * NPIX4) return;
    int bi = tid / NPIX4;
    int pq = tid - bi * NPIX4;
    int p0 = pq * 4;            // base pixel index, 16B-aligned per channel
    int y  = p0 / IW;
    int x0 = p0 - y * IW;       // all 4 pixels share row y

    const float* Ki = Kinv + bi * 9;
    const float k00 = Ki[0], k01 = Ki[1], k02 = Ki[2];
    const float k10 = Ki[3], k11 = Ki[4], k12 = Ki[5];
    const float k20 = Ki[6], k21 = Ki[7], k22 = Ki[8];

    const float fy = (float)y;
    // rays at the 4 destination pixels
    float rd0[4], rd1[4], rd2[4];
#pragma unroll
    for (int i = 0; i < 4; ++i) {
        const float fx = (float)(x0 + i);
        rd0[i] = k00 * fx + k01 * fy + k02;
        rd1[i] = k10 * fx + k11 * fy + k12;
        rd2[i] = k20 * fx + k21 * fy + k22;
    }

    const float* dp = depth  + (size_t)bi * IHW;
    const float* cf = conf   + (size_t)bi * IHW;
    const float* nr = normal + (size_t)bi * 3 * IHW;
    const float* rg = rgb    + (size_t)bi * 3 * IHW;

    const f32x4 dctr = *reinterpret_cast<const f32x4*>(dp + p0);
    const float dc[4] = { dctr.x, dctr.y, dctr.z, dctr.w };

    float* outb = out + (size_t)bi * 24 * 5 * IHW + p0;

    // 8 (axis, dir) combos in reference order: ud d1/d2, lr d1/d2, lu d1/d2, ld d1/d2
    const int uy[8] = { -1, +1,  0,  0, -1, +1, -1, +1 };
    const int ux[8] = {  0,  0, -1, +1, -1, +1, +1, -1 };

#pragma unroll
    for (int oi = 0; oi < 3; ++oi) {
        const int o = 2 * oi + 1;   // 1, 3, 5
#pragma unroll
        for (int k = 0; k < 8; ++k) {
            const int oy = uy[k] * o;
            const int ox = ux[k] * o;
            const int sy = y + oy;
            const int c  = oi * 8 + k;
            float* ob = outb + (size_t)c * 5 * IHW;

            // per-combo constants: e = K_inv * (ox, oy, 0)
            const float fox = (float)ox, foy = (float)oy;
            const float e0 = fox * k00 + foy * k01;
            const float e1 = fox * k10 + foy * k11;
            const float e2 = fox * k20 + foy * k21;

            float od[4], oc[4], og0[4], og1[4], og2[4];
            const bool rowin = (sy >= 0) & (sy < IH);
            if (rowin) {
                const int srow = sy * IW;
#pragma unroll
                for (int i = 0; i < 4; ++i) {
                    const int sx = x0 + i + ox;
                    if (sx >= 0 && sx < IW) {
                        const int sp = srow + sx;
                        const float n0 = nr[sp];
                        const float n1 = nr[IHW + sp];
                        const float n2 = nr[2 * IHW + sp];
                        const float ds = dp[sp];
                        oc[i]  = cf[sp];
                        og0[i] = rg[sp];
                        og1[i] = rg[IHW + sp];
                        og2[i] = rg[2 * IHW + sp];
                        // den = n_s . ray_dest ; nom = d_s * (den + n_s . e)
                        const float den = n0 * rd0[i] + n1 * rd1[i] + n2 * rd2[i];
                        const float t   = den + n0 * e0 + n1 * e1 + n2 * e2;
                        const float v   = ds * t * __builtin_amdgcn_rcpf(den + 1e-18f);
                        od[i] = fminf(fmaxf(v, 0.01f), 10.0f);
                    } else {
                        od[i] = dc[i];
                        oc[i] = 0.0f; og0[i] = 0.0f; og1[i] = 0.0f; og2[i] = 0.0f;
                    }
                }
            } else {
#pragma unroll
                for (int i = 0; i < 4; ++i) {
                    const int sx = x0 + i + ox;
                    // ld-d2 quirk: bottom boundary passes depth[y, x-o] through
                    if (k == 7 && sy >= IH && sx >= 0) od[i] = dp[y * IW + sx];
                    else                               od[i] = dc[i];
                    oc[i] = 0.0f; og0[i] = 0.0f; og1[i] = 0.0f; og2[i] = 0.0f;
                }
            }

            f32x4 v4;
            v4 = (f32x4){ od[0],  od[1],  od[2],  od[3]  };
            __builtin_nontemporal_store(v4, reinterpret_cast<f32x4*>(ob));
            v4 = (f32x4){ oc[0],  oc[1],  oc[2],  oc[3]  };
            __builtin_nontemporal_store(v4, reinterpret_cast<f32x4*>(ob + IHW));
            v4 = (f32x4){ og0[0], og0[1], og0[2], og0[3] };
            __builtin_nontemporal_store(v4, reinterpret_cast<f32x4*>(ob + 2 * IHW));
            v4 = (f32x4){ og1[0], og1[1], og1[2], og1[3] };
            __builtin_nontemporal_store(v4, reinterpret_cast<f32x4*>(ob + 3 * IHW));
            v4 = (f32x4){ og2[0], og2[1], og2[2], og2[3] };
            __builtin_nontemporal_store(v4, reinterpret_cast<f32x4*>(ob + 4 * IHW));
        }
    }
}

extern "C" void kernel_launch(void* const* d_in, const int* in_sizes, int n_in,
                              void* d_out, int out_size, void* d_ws, size_t ws_size,
                              hipStream_t stream) {
    const float* depth  = (const float*)d_in[0];
    const float* normal = (const float*)d_in[1];
    const float* rgb    = (const float*)d_in[2];
    const float* conf   = (const float*)d_in[3];
    const float* Kinv   = (const float*)d_in[4];
    float* out = (float*)d_out;

    const int B = in_sizes[0] / IHW;
    const int total = B * NPIX4;
    const int block = 256;
    const int grid = (total + block - 1) / block;

    hipLaunchKernelGGL(prop_kernel, dim3(grid), dim3(block), 0, stream,
                       depth, normal, rgb, conf, Kinv, out, B);
}

// Round 4
// 83.423 us; speedup vs baseline: 1.8125x; 1.8125x over previous
//
#include <hip/hip_runtime.h>

static constexpr int IH = 480;
static constexpr int IW = 640;
static constexpr int IHW = IH * IW;

// 8 (axis, dir) combos in reference order:
// ud d1, ud d2, lr d1, lr d2, lu d1, lu d2, ld d1, ld d2
__device__ __constant__ const int c_oy[8] = { -1, +1,  0,  0, -1, +1, -1, +1 };
__device__ __constant__ const int c_ox[8] = {  0,  0, -1, +1, -1, +1, +1, -1 };

__global__ __launch_bounds__(256) void prop_kernel(
    const float* __restrict__ depth,
    const float* __restrict__ normal,
    const float* __restrict__ rgb,
    const float* __restrict__ conf,
    const float* __restrict__ Kinv,
    float* __restrict__ out,
    int B)
{
    int idx = blockIdx.x * blockDim.x + threadIdx.x;
    int total = B * IHW;
    if (idx >= total) return;

    int bi = idx / IHW;
    int p  = idx - bi * IHW;
    int y  = p / IW;
    int x  = p - y * IW;

    const float* Ki = Kinv + bi * 9;
    const float k00 = Ki[0], k01 = Ki[1], k02 = Ki[2];
    const float k10 = Ki[3], k11 = Ki[4], k12 = Ki[5];
    const float k20 = Ki[6], k21 = Ki[7], k22 = Ki[8];

    const float fx = (float)x, fy = (float)y;
    // ray at the OUTPUT pixel: K_inv * (x, y, 1)
    const float r0 = k00 * fx + k01 * fy + k02;
    const float r1 = k10 * fx + k11 * fy + k12;
    const float r2 = k20 * fx + k21 * fy + k22;

    const float* dp = depth + (size_t)bi * IHW;
    const float* cf = conf  + (size_t)bi * IHW;
    const float* nr = normal + (size_t)bi * 3 * IHW;
    const float* rg = rgb    + (size_t)bi * 3 * IHW;

    const float dcenter = dp[p];

    float* outb = out + (size_t)bi * 24 * 5 * IHW + p;

#pragma unroll
    for (int oi = 0; oi < 3; ++oi) {
        const int o = 2 * oi + 1;  // 1, 3, 5
#pragma unroll
        for (int k = 0; k < 8; ++k) {
            const int oy = c_oy[k] * o;
            const int ox = c_ox[k] * o;
            const int sy = y + oy;
            const int sx = x + ox;
            const int c  = oi * 8 + k;
            float* ob = outb + (size_t)c * 5 * IHW;

            float od, oc, og0, og1, og2;
            const bool inb = (sx >= 0) & (sx < IW) & (sy >= 0) & (sy < IH);
            if (inb) {
                const int sp = sy * IW + sx;
                const float n0 = nr[sp];
                const float n1 = nr[IHW + sp];
                const float n2 = nr[2 * IHW + sp];
                const float ds = dp[sp];
                oc  = cf[sp];
                og0 = rg[sp];
                og1 = rg[IHW + sp];
                og2 = rg[2 * IHW + sp];

                // ray at the SOURCE pixel = ray_out + ox*Kcol0 + oy*Kcol1
                const float fox = (float)ox, foy = (float)oy;
                const float s0 = r0 + fox * k00 + foy * k01;
                const float s1 = r1 + fox * k10 + foy * k11;
                const float s2 = r2 + fox * k20 + foy * k21;

                const float nom = ds * (n0 * s0 + n1 * s1 + n2 * s2);
                const float den = n0 * r0 + n1 * r1 + n2 * r2;  // n_s . ray_out
                const float v   = nom * __builtin_amdgcn_rcpf(den + 1e-18f);
                od = fminf(fmaxf(v, 0.01f), 10.0f);
            } else {
                // boundary: depth passes through, conf/rgb are zero.
                // ld-d2 (k==7) bottom boundary uses depth[y, x-o] == depth[y, sx].
                if (k == 7 && sx >= 0 && sy >= IH) {
                    od = dp[y * IW + sx];
                } else {
                    od = dcenter;
                }
                oc = 0.0f; og0 = 0.0f; og1 = 0.0f; og2 = 0.0f;
            }

            __builtin_nontemporal_store(od,  ob);
            __builtin_nontemporal_store(oc,  ob + IHW);
            __builtin_nontemporal_store(og0, ob + 2 * IHW);
            __builtin_nontemporal_store(og1, ob + 3 * IHW);
            __builtin_nontemporal_store(og2, ob + 4 * IHW);
        }
    }
}

extern "C" void kernel_launch(void* const* d_in, const int* in_sizes, int n_in,
                              void* d_out, int out_size, void* d_ws, size_t ws_size,
                              hipStream_t stream) {
    const float* depth  = (const float*)d_in[0];
    const float* normal = (const float*)d_in[1];
    const float* rgb    = (const float*)d_in[2];
    const float* conf   = (const float*)d_in[3];
    const float* Kinv   = (const float*)d_in[4];
    float* out = (float*)d_out;

    const int B = in_sizes[0] / IHW;
    const int total = B * IHW;
    const int block = 256;
    const int grid = (total + block - 1) / block;

    hipLaunchKernelGGL(prop_kernel, dim3(grid), dim3(block), 0, stream,
                       depth, normal, rgb, conf, Kinv, out, B);
}

// Round 5
// 75.206 us; speedup vs baseline: 2.0106x; 1.1093x over previous
//
#include <hip/hip_runtime.h>

static constexpr int IH = 480;
static constexpr int IW = 640;
static constexpr int IHW = IH * IW;

// 8 (axis, dir) combos in reference order:
// ud d1, ud d2, lr d1, lr d2, lu d1, lu d2, ld d1, ld d2
__device__ __constant__ const int c_oy[8] = { -1, +1,  0,  0, -1, +1, -1, +1 };
__device__ __constant__ const int c_ox[8] = {  0,  0, -1, +1, -1, +1, +1, -1 };

__global__ __launch_bounds__(256) void prop_kernel(
    const float* __restrict__ depth,
    const float* __restrict__ normal,
    const float* __restrict__ rgb,
    const float* __restrict__ conf,
    const float* __restrict__ Kinv,
    float* __restrict__ out)
{
    const int c  = blockIdx.y;          // combo 0..23
    const int bi = blockIdx.z;          // batch
    const int p  = blockIdx.x * 256 + threadIdx.x;
    const int y  = p / IW;
    const int x  = p - y * IW;

    const int oi = c >> 3;              // offset index 0,1,2
    const int k  = c & 7;               // axis/dir combo
    const int o  = 2 * oi + 1;          // 1, 3, 5
    const int oy = c_oy[k] * o;
    const int ox = c_ox[k] * o;

    const float* Ki = Kinv + bi * 9;
    const float k00 = Ki[0], k01 = Ki[1], k02 = Ki[2];
    const float k10 = Ki[3], k11 = Ki[4], k12 = Ki[5];
    const float k20 = Ki[6], k21 = Ki[7], k22 = Ki[8];

    const float fx = (float)x, fy = (float)y;
    // ray at the OUTPUT pixel: K_inv * (x, y, 1)
    const float r0 = k00 * fx + k01 * fy + k02;
    const float r1 = k10 * fx + k11 * fy + k12;
    const float r2 = k20 * fx + k21 * fy + k22;
    // per-combo ray delta: e = K_inv * (ox, oy, 0)
    const float fox = (float)ox, foy = (float)oy;
    const float e0 = fox * k00 + foy * k01;
    const float e1 = fox * k10 + foy * k11;
    const float e2 = fox * k20 + foy * k21;

    const float* dp = depth  + (size_t)bi * IHW;
    const float* cf = conf   + (size_t)bi * IHW;
    const float* nr = normal + (size_t)bi * 3 * IHW;
    const float* rg = rgb    + (size_t)bi * 3 * IHW;

    const int sy = y + oy;
    const int sx = x + ox;

    float od, oc, og0, og1, og2;
    const bool inb = (sx >= 0) & (sx < IW) & (sy >= 0) & (sy < IH);
    if (inb) {
        const int sp = sy * IW + sx;
        const float n0 = nr[sp];
        const float n1 = nr[IHW + sp];
        const float n2 = nr[2 * IHW + sp];
        const float ds = dp[sp];
        oc  = cf[sp];
        og0 = rg[sp];
        og1 = rg[IHW + sp];
        og2 = rg[2 * IHW + sp];

        const float den = n0 * r0 + n1 * r1 + n2 * r2;        // n_s . ray_dest
        const float t   = den + n0 * e0 + n1 * e1 + n2 * e2;  // n_s . ray_src
        const float v   = ds * t * __builtin_amdgcn_rcpf(den + 1e-18f);
        od = fminf(fmaxf(v, 0.01f), 10.0f);
    } else {
        // boundary: depth passes through, conf/rgb are zero.
        // ld-d2 (k==7) bottom boundary uses depth[y, x-o] == depth[y, sx].
        if (k == 7 && sx >= 0 && sy >= IH) od = dp[y * IW + sx];
        else                               od = dp[p];
        oc = 0.0f; og0 = 0.0f; og1 = 0.0f; og2 = 0.0f;
    }

    float* ob = out + (((size_t)bi * 24 + c) * 5) * IHW + p;
    __builtin_nontemporal_store(od,  ob);
    __builtin_nontemporal_store(oc,  ob + IHW);
    __builtin_nontemporal_store(og0, ob + 2 * IHW);
    __builtin_nontemporal_store(og1, ob + 3 * IHW);
    __builtin_nontemporal_store(og2, ob + 4 * IHW);
}

extern "C" void kernel_launch(void* const* d_in, const int* in_sizes, int n_in,
                              void* d_out, int out_size, void* d_ws, size_t ws_size,
                              hipStream_t stream) {
    const float* depth  = (const float*)d_in[0];
    const float* normal = (const float*)d_in[1];
    const float* rgb    = (const float*)d_in[2];
    const float* conf   = (const float*)d_in[3];
    const float* Kinv   = (const float*)d_in[4];
    float* out = (float*)d_out;

    const int B = in_sizes[0] / IHW;
    dim3 grid(IHW / 256, 24, B);
    dim3 block(256, 1, 1);

    hipLaunchKernelGGL(prop_kernel, grid, block, 0, stream,
                       depth, normal, rgb, conf, Kinv, out);
}